// Round 1
// baseline (393.952 us; speedup 1.0000x reference)
//
#include <hip/hip_runtime.h>
#include <stdint.h>

#define NPTS 1048576

using u16x8 = __attribute__((ext_vector_type(8))) unsigned short;
using f32x4 = __attribute__((ext_vector_type(4))) float;

__device__ __forceinline__ float bf2f(unsigned short u) {
    union { unsigned int i; float f; } c; c.i = ((unsigned int)u) << 16; return c.f;
}
__device__ __forceinline__ unsigned int f2bf_bits(float f) {
    union { float f; unsigned int i; } c; c.f = f;
    unsigned int i = c.i;
    i += 0x7fffu + ((i >> 16) & 1u);   // round-to-nearest-even
    return i >> 16;
}

// ---------------------------------------------------------------------------
// Phase 1: transpose (C=32, H, W) fp32  ->  (H, W, C=32) bf16 into workspace.
// One block handles a (32 c) x (WC w) tile of one row h. blockIdx.y = plane.
// ---------------------------------------------------------------------------
template<int WC, int H, int W>
__global__ __launch_bounds__(256) void transpose3(const float* __restrict__ s0,
                                                  const float* __restrict__ s1,
                                                  const float* __restrict__ s2,
                                                  unsigned short* __restrict__ dst) {
    __shared__ float tile[32][WC + 1];
    const float* src = (blockIdx.y == 0) ? s0 : (blockIdx.y == 1) ? s1 : s2;
    constexpr int CH = W / WC;                 // chunks per row
    const int h  = blockIdx.x / CH;
    const int w0 = (blockIdx.x % CH) * WC;
    const int HW = H * W;
    const float* s = src + h * W + w0;
    for (int i = threadIdx.x; i < 32 * WC; i += 256) {
        int c = i / WC, w = i - c * WC;
        tile[c][w] = s[c * HW + w];            // coalesced over w
    }
    __syncthreads();
    unsigned int* d = (unsigned int*)(dst + (size_t)blockIdx.y * HW * 32
                                          + (size_t)(h * W + w0) * 32);
    for (int i = threadIdx.x; i < 16 * WC; i += 256) {
        int w = i >> 4, cp = i & 15;
        unsigned int lo = f2bf_bits(tile[cp * 2][w]);
        unsigned int hi = f2bf_bits(tile[cp * 2 + 1][w]);
        d[i] = lo | (hi << 16);                // coalesced bf16x2 writes
    }
}

// ---------------------------------------------------------------------------
// Phase 2: per-point bilinear sample from the (H,W,C) bf16 planes.
// 4 threads per point; thread `sub` owns features [8*sub, 8*sub+8).
// ---------------------------------------------------------------------------
template<int W, int H>
__device__ __forceinline__ void sample_one(const unsigned short* __restrict__ pl,
                                           float gw, float gh, int sub,
                                           float* __restrict__ o) {
    float ix = (gw + 1.0f) * 0.5f * (float)(W - 1);
    float iy = (gh + 1.0f) * 0.5f * (float)(H - 1);
    float fx0 = fminf(fmaxf(floorf(ix), 0.0f), (float)(W - 1));
    float fy0 = fminf(fmaxf(floorf(iy), 0.0f), (float)(H - 1));
    int ix0 = (int)fx0, iy0 = (int)fy0;
    int ix1 = min(ix0 + 1, W - 1), iy1 = min(iy0 + 1, H - 1);
    float wx = ix - fx0, wy = iy - fy0;
    float wx0 = 1.0f - wx, wy0 = 1.0f - wy;
    float w00 = wx0 * wy0, w01 = wx * wy0, w10 = wx0 * wy, w11 = wx * wy;
    const int base = sub * 8;
    u16x8 v00 = *(const u16x8*)(pl + ((iy0 * W + ix0) * 32 + base));
    u16x8 v01 = *(const u16x8*)(pl + ((iy0 * W + ix1) * 32 + base));
    u16x8 v10 = *(const u16x8*)(pl + ((iy1 * W + ix0) * 32 + base));
    u16x8 v11 = *(const u16x8*)(pl + ((iy1 * W + ix1) * 32 + base));
    f32x4 r0, r1;
#pragma unroll
    for (int j = 0; j < 4; ++j)
        r0[j] = bf2f(v00[j]) * w00 + bf2f(v01[j]) * w01
              + bf2f(v10[j]) * w10 + bf2f(v11[j]) * w11;
#pragma unroll
    for (int j = 0; j < 4; ++j)
        r1[j] = bf2f(v00[4 + j]) * w00 + bf2f(v01[4 + j]) * w01
              + bf2f(v10[4 + j]) * w10 + bf2f(v11[4 + j]) * w11;
    *(f32x4*)(o)     = r0;
    *(f32x4*)(o + 4) = r1;
}

__global__ __launch_bounds__(256) void sample_kernel(const float* __restrict__ x,
                                                     const unsigned short* __restrict__ ws,
                                                     float* __restrict__ out) {
    int tid = blockIdx.x * 256 + threadIdx.x;
    int p   = tid >> 2;
    int sub = tid & 3;
    f32x4 xv = *(const f32x4*)(x + (size_t)p * 4);
    float gx = (xv[0] * 0.5f + 0.5f) * 2.0f - 1.0f;
    float gy = (xv[1] * 0.5f + 0.5f) * 2.0f - 1.0f;
    float gz = (xv[2] * 0.5f + 0.5f) * 2.0f - 1.0f;
    float gt = (xv[3] * 0.5f + 0.5f) * 2.0f - 1.0f;
    float* o = out + (size_t)p * 192 + sub * 8;
    sample_one<512, 512>(ws + 0ul,        gx, gy, sub, o + 0);
    sample_one<512, 512>(ws + 8388608ul,  gx, gz, sub, o + 32);
    sample_one<512, 512>(ws + 16777216ul, gy, gz, sub, o + 64);
    sample_one<16,  512>(ws + 25165824ul, gx, gt, sub, o + 96);
    sample_one<16,  512>(ws + 25427968ul, gy, gt, sub, o + 128);
    sample_one<16,  512>(ws + 25690112ul, gz, gt, sub, o + 160);
}

// ---------------------------------------------------------------------------
// Fallback (workspace too small): sample directly from (C,H,W) fp32 planes.
// Correct but slow; insurance against harness ws sizing.
// ---------------------------------------------------------------------------
template<int W, int H>
__device__ __forceinline__ void sample_direct_one(const float* __restrict__ pl,
                                                  float gw, float gh, int sub,
                                                  float* __restrict__ o) {
    float ix = (gw + 1.0f) * 0.5f * (float)(W - 1);
    float iy = (gh + 1.0f) * 0.5f * (float)(H - 1);
    float fx0 = fminf(fmaxf(floorf(ix), 0.0f), (float)(W - 1));
    float fy0 = fminf(fmaxf(floorf(iy), 0.0f), (float)(H - 1));
    int ix0 = (int)fx0, iy0 = (int)fy0;
    int ix1 = min(ix0 + 1, W - 1), iy1 = min(iy0 + 1, H - 1);
    float wx = ix - fx0, wy = iy - fy0;
    float wx0 = 1.0f - wx, wy0 = 1.0f - wy;
    float w00 = wx0 * wy0, w01 = wx * wy0, w10 = wx0 * wy, w11 = wx * wy;
    const int HW = W * H;
    int a00 = iy0 * W + ix0, a01 = iy0 * W + ix1;
    int a10 = iy1 * W + ix0, a11 = iy1 * W + ix1;
    const float* b = pl + (size_t)sub * 8 * HW;
#pragma unroll
    for (int j = 0; j < 8; ++j) {
        o[j] = b[a00] * w00 + b[a01] * w01 + b[a10] * w10 + b[a11] * w11;
        b += HW;
    }
}

__global__ __launch_bounds__(256) void sample_fallback(const float* __restrict__ x,
    const float* __restrict__ pxy, const float* __restrict__ pxz,
    const float* __restrict__ pyz, const float* __restrict__ pxt,
    const float* __restrict__ pyt, const float* __restrict__ pzt,
    float* __restrict__ out) {
    int tid = blockIdx.x * 256 + threadIdx.x;
    int p   = tid >> 2;
    int sub = tid & 3;
    f32x4 xv = *(const f32x4*)(x + (size_t)p * 4);
    float gx = (xv[0] * 0.5f + 0.5f) * 2.0f - 1.0f;
    float gy = (xv[1] * 0.5f + 0.5f) * 2.0f - 1.0f;
    float gz = (xv[2] * 0.5f + 0.5f) * 2.0f - 1.0f;
    float gt = (xv[3] * 0.5f + 0.5f) * 2.0f - 1.0f;
    float* o = out + (size_t)p * 192 + sub * 8;
    sample_direct_one<512, 512>(pxy, gx, gy, sub, o + 0);
    sample_direct_one<512, 512>(pxz, gx, gz, sub, o + 32);
    sample_direct_one<512, 512>(pyz, gy, gz, sub, o + 64);
    sample_direct_one<16,  512>(pxt, gx, gt, sub, o + 96);
    sample_direct_one<16,  512>(pyt, gy, gt, sub, o + 128);
    sample_direct_one<16,  512>(pzt, gz, gt, sub, o + 160);
}

extern "C" void kernel_launch(void* const* d_in, const int* in_sizes, int n_in,
                              void* d_out, int out_size, void* d_ws, size_t ws_size,
                              hipStream_t stream) {
    const float* x   = (const float*)d_in[0];
    const float* pxy = (const float*)d_in[1];
    const float* pxz = (const float*)d_in[2];
    const float* pyz = (const float*)d_in[3];
    const float* pxt = (const float*)d_in[4];
    const float* pyt = (const float*)d_in[5];
    const float* pzt = (const float*)d_in[6];
    float* out = (float*)d_out;

    const size_t need_elems = 25952256ull;          // bf16 elements
    const size_t need_bytes = need_elems * 2;       // ~49.5 MiB

    if (ws_size >= need_bytes) {
        unsigned short* ws = (unsigned short*)d_ws;
        // big planes: (32,512,512) -> (512*512, 32) bf16
        transpose3<64, 512, 512><<<dim3(512 * 8, 3), 256, 0, stream>>>(pxy, pxz, pyz, ws);
        // small planes: (32,512,16) -> (512*16, 32) bf16
        transpose3<16, 512, 16><<<dim3(512, 3), 256, 0, stream>>>(pxt, pyt, pzt, ws + 25165824ul);
        sample_kernel<<<(NPTS * 4) / 256, 256, 0, stream>>>(x, ws, out);
    } else {
        sample_fallback<<<(NPTS * 4) / 256, 256, 0, stream>>>(x, pxy, pxz, pyz, pxt, pyt, pzt, out);
    }
}

// Round 2
// 372.561 us; speedup vs baseline: 1.0574x; 1.0574x over previous
//
#include <hip/hip_runtime.h>
#include <stdint.h>

#define NPTS 1048576
#define NBINS 32768

using u16x8 = __attribute__((ext_vector_type(8))) unsigned short;
using f32x4 = __attribute__((ext_vector_type(4))) float;

// workspace byte offsets
#define OFF_HIST     51904512ul
#define OFF_CURSOR   52035584ul
#define OFF_KEYS     52166656ul
#define OFF_XS       54263808ul
#define OFF_PID      71041024ul
#define WS_NEED_FULL 75235328ul
#define WS_NEED_MID  51904512ul

__device__ __forceinline__ float bf2f(unsigned short u) {
    union { unsigned int i; float f; } c; c.i = ((unsigned int)u) << 16; return c.f;
}
__device__ __forceinline__ unsigned int f2bf_bits(float f) {
    union { float f; unsigned int i; } c; c.f = f;
    unsigned int i = c.i;
    i += 0x7fffu + ((i >> 16) & 1u);   // round-to-nearest-even
    return i >> 16;
}
__device__ __forceinline__ unsigned int spread3(unsigned int v) {
    v &= 31u;
    v = (v | (v << 8)) & 0x100Fu;
    v = (v | (v << 4)) & 0x10C3u;
    v = (v | (v << 2)) & 0x1249u;   // bits at 0,3,6,9,12
    return v;
}

// ---------------------------------------------------------------------------
// Phase 1: transpose (C=32, H, W) fp32  ->  (H, W, C=32) bf16 into workspace.
// ---------------------------------------------------------------------------
template<int WC, int H, int W>
__global__ __launch_bounds__(256) void transpose3(const float* __restrict__ s0,
                                                  const float* __restrict__ s1,
                                                  const float* __restrict__ s2,
                                                  unsigned short* __restrict__ dst) {
    __shared__ float tile[32][WC + 1];
    const float* src = (blockIdx.y == 0) ? s0 : (blockIdx.y == 1) ? s1 : s2;
    constexpr int CH = W / WC;
    const int h  = blockIdx.x / CH;
    const int w0 = (blockIdx.x % CH) * WC;
    const int HW = H * W;
    const float* s = src + h * W + w0;
    for (int i = threadIdx.x; i < 32 * WC; i += 256) {
        int c = i / WC, w = i - c * WC;
        tile[c][w] = s[c * HW + w];
    }
    __syncthreads();
    unsigned int* d = (unsigned int*)(dst + (size_t)blockIdx.y * HW * 32
                                          + (size_t)(h * W + w0) * 32);
    for (int i = threadIdx.x; i < 16 * WC; i += 256) {
        int w = i >> 4, cp = i & 15;
        unsigned int lo = f2bf_bits(tile[cp * 2][w]);
        unsigned int hi = f2bf_bits(tile[cp * 2 + 1][w]);
        d[i] = lo | (hi << 16);
    }
}

// ---------------------------------------------------------------------------
// Sort pipeline: histogram -> scan -> scatter (counting sort by Morton key)
// ---------------------------------------------------------------------------
__global__ __launch_bounds__(256) void hist_kernel(const float* __restrict__ x,
                                                   unsigned int* __restrict__ hist,
                                                   unsigned short* __restrict__ keys) {
    int p = blockIdx.x * 256 + threadIdx.x;
    f32x4 xv = *(const f32x4*)(x + (size_t)p * 4);
    int bx = min(31, max(0, (int)((xv[0] + 1.0f) * 16.0f)));
    int by = min(31, max(0, (int)((xv[1] + 1.0f) * 16.0f)));
    int bz = min(31, max(0, (int)((xv[2] + 1.0f) * 16.0f)));
    unsigned int key = (spread3(bx) << 2) | (spread3(by) << 1) | spread3(bz);
    keys[p] = (unsigned short)key;
    atomicAdd(&hist[key], 1u);
}

__global__ __launch_bounds__(1024) void scan_kernel(const unsigned int* __restrict__ hist,
                                                    unsigned int* __restrict__ cursor) {
    __shared__ unsigned int part[1024];
    int t = threadIdx.x;
    unsigned int local[32];
    unsigned int s = 0;
    int base = t * 32;
#pragma unroll
    for (int j = 0; j < 32; ++j) { local[j] = s; s += hist[base + j]; }
    part[t] = s;
    __syncthreads();
    for (int off = 1; off < 1024; off <<= 1) {
        unsigned int v = 0;
        if (t >= off) v = part[t - off];
        __syncthreads();
        if (t >= off) part[t] += v;
        __syncthreads();
    }
    unsigned int chunkbase = part[t] - s;   // exclusive
#pragma unroll
    for (int j = 0; j < 32; ++j) cursor[base + j] = chunkbase + local[j];
}

__global__ __launch_bounds__(256) void scatter_kernel(const float* __restrict__ x,
                                                      const unsigned short* __restrict__ keys,
                                                      unsigned int* __restrict__ cursor,
                                                      f32x4* __restrict__ xs,
                                                      unsigned int* __restrict__ pid) {
    int p = blockIdx.x * 256 + threadIdx.x;
    f32x4 xv = *(const f32x4*)(x + (size_t)p * 4);
    unsigned int k = keys[p];
    unsigned int pos = atomicAdd(&cursor[k], 1u);
    xs[pos] = xv;
    pid[pos] = (unsigned int)p;
}

// ---------------------------------------------------------------------------
// Bilinear sample from (H,W,C) bf16 plane; 4 threads/point, 8 feats each.
// ---------------------------------------------------------------------------
template<int W, int H, bool NT>
__device__ __forceinline__ void sample_one(const unsigned short* __restrict__ pl,
                                           float gw, float gh, int sub,
                                           float* __restrict__ o) {
    float ix = (gw + 1.0f) * 0.5f * (float)(W - 1);
    float iy = (gh + 1.0f) * 0.5f * (float)(H - 1);
    float fx0 = fminf(fmaxf(floorf(ix), 0.0f), (float)(W - 1));
    float fy0 = fminf(fmaxf(floorf(iy), 0.0f), (float)(H - 1));
    int ix0 = (int)fx0, iy0 = (int)fy0;
    int ix1 = min(ix0 + 1, W - 1), iy1 = min(iy0 + 1, H - 1);
    float wx = ix - fx0, wy = iy - fy0;
    float wx0 = 1.0f - wx, wy0 = 1.0f - wy;
    float w00 = wx0 * wy0, w01 = wx * wy0, w10 = wx0 * wy, w11 = wx * wy;
    const int base = sub * 8;
    u16x8 v00 = *(const u16x8*)(pl + ((iy0 * W + ix0) * 32 + base));
    u16x8 v01 = *(const u16x8*)(pl + ((iy0 * W + ix1) * 32 + base));
    u16x8 v10 = *(const u16x8*)(pl + ((iy1 * W + ix0) * 32 + base));
    u16x8 v11 = *(const u16x8*)(pl + ((iy1 * W + ix1) * 32 + base));
    f32x4 r0, r1;
#pragma unroll
    for (int j = 0; j < 4; ++j)
        r0[j] = bf2f(v00[j]) * w00 + bf2f(v01[j]) * w01
              + bf2f(v10[j]) * w10 + bf2f(v11[j]) * w11;
#pragma unroll
    for (int j = 0; j < 4; ++j)
        r1[j] = bf2f(v00[4 + j]) * w00 + bf2f(v01[4 + j]) * w01
              + bf2f(v10[4 + j]) * w10 + bf2f(v11[4 + j]) * w11;
    if (NT) {
        __builtin_nontemporal_store(r0, (f32x4*)(o));
        __builtin_nontemporal_store(r1, (f32x4*)(o + 4));
    } else {
        *(f32x4*)(o)     = r0;
        *(f32x4*)(o + 4) = r1;
    }
}

__device__ __forceinline__ void sample_all(f32x4 xv, int sub,
                                           const unsigned short* __restrict__ ws,
                                           float* __restrict__ o) {
    float gx = (xv[0] * 0.5f + 0.5f) * 2.0f - 1.0f;
    float gy = (xv[1] * 0.5f + 0.5f) * 2.0f - 1.0f;
    float gz = (xv[2] * 0.5f + 0.5f) * 2.0f - 1.0f;
    float gt = (xv[3] * 0.5f + 0.5f) * 2.0f - 1.0f;
    sample_one<512, 512, true>(ws + 0ul,        gx, gy, sub, o + 0);
    sample_one<512, 512, true>(ws + 8388608ul,  gx, gz, sub, o + 32);
    sample_one<512, 512, true>(ws + 16777216ul, gy, gz, sub, o + 64);
    sample_one<16,  512, true>(ws + 25165824ul, gx, gt, sub, o + 96);
    sample_one<16,  512, true>(ws + 25427968ul, gy, gt, sub, o + 128);
    sample_one<16,  512, true>(ws + 25690112ul, gz, gt, sub, o + 160);
}

// Sorted-order sampler: blocks XCD-swizzled so each XCD works a contiguous
// Morton range (compact plane footprint per XCD L2).
__global__ __launch_bounds__(256) void sample_sorted(const f32x4* __restrict__ xs,
                                                     const unsigned int* __restrict__ pid,
                                                     const unsigned short* __restrict__ ws,
                                                     float* __restrict__ out) {
    int nwg = gridDim.x;                       // 16384, divisible by 8
    int cpx = nwg >> 3;
    int bid = blockIdx.x;
    int swz = (bid & 7) * cpx + (bid >> 3);
    int tid = swz * 256 + threadIdx.x;
    int s   = tid >> 2;
    int sub = tid & 3;
    f32x4 xv = xs[s];
    int p = pid[s];
    sample_all(xv, sub, ws, out + (size_t)p * 192 + sub * 8);
}

// Unsorted sampler (mid fallback)
__global__ __launch_bounds__(256) void sample_kernel(const float* __restrict__ x,
                                                     const unsigned short* __restrict__ ws,
                                                     float* __restrict__ out) {
    int tid = blockIdx.x * 256 + threadIdx.x;
    int p   = tid >> 2;
    int sub = tid & 3;
    f32x4 xv = *(const f32x4*)(x + (size_t)p * 4);
    sample_all(xv, sub, ws, out + (size_t)p * 192 + sub * 8);
}

// ---------------------------------------------------------------------------
// Last-resort fallback: direct strided fp32 sampling from (C,H,W).
// ---------------------------------------------------------------------------
template<int W, int H>
__device__ __forceinline__ void sample_direct_one(const float* __restrict__ pl,
                                                  float gw, float gh, int sub,
                                                  float* __restrict__ o) {
    float ix = (gw + 1.0f) * 0.5f * (float)(W - 1);
    float iy = (gh + 1.0f) * 0.5f * (float)(H - 1);
    float fx0 = fminf(fmaxf(floorf(ix), 0.0f), (float)(W - 1));
    float fy0 = fminf(fmaxf(floorf(iy), 0.0f), (float)(H - 1));
    int ix0 = (int)fx0, iy0 = (int)fy0;
    int ix1 = min(ix0 + 1, W - 1), iy1 = min(iy0 + 1, H - 1);
    float wx = ix - fx0, wy = iy - fy0;
    float wx0 = 1.0f - wx, wy0 = 1.0f - wy;
    float w00 = wx0 * wy0, w01 = wx * wy0, w10 = wx0 * wy, w11 = wx * wy;
    const int HW = W * H;
    int a00 = iy0 * W + ix0, a01 = iy0 * W + ix1;
    int a10 = iy1 * W + ix0, a11 = iy1 * W + ix1;
    const float* b = pl + (size_t)sub * 8 * HW;
#pragma unroll
    for (int j = 0; j < 8; ++j) {
        o[j] = b[a00] * w00 + b[a01] * w01 + b[a10] * w10 + b[a11] * w11;
        b += HW;
    }
}

__global__ __launch_bounds__(256) void sample_fallback(const float* __restrict__ x,
    const float* __restrict__ pxy, const float* __restrict__ pxz,
    const float* __restrict__ pyz, const float* __restrict__ pxt,
    const float* __restrict__ pyt, const float* __restrict__ pzt,
    float* __restrict__ out) {
    int tid = blockIdx.x * 256 + threadIdx.x;
    int p   = tid >> 2;
    int sub = tid & 3;
    f32x4 xv = *(const f32x4*)(x + (size_t)p * 4);
    float gx = (xv[0] * 0.5f + 0.5f) * 2.0f - 1.0f;
    float gy = (xv[1] * 0.5f + 0.5f) * 2.0f - 1.0f;
    float gz = (xv[2] * 0.5f + 0.5f) * 2.0f - 1.0f;
    float gt = (xv[3] * 0.5f + 0.5f) * 2.0f - 1.0f;
    float* o = out + (size_t)p * 192 + sub * 8;
    sample_direct_one<512, 512>(pxy, gx, gy, sub, o + 0);
    sample_direct_one<512, 512>(pxz, gx, gz, sub, o + 32);
    sample_direct_one<512, 512>(pyz, gy, gz, sub, o + 64);
    sample_direct_one<16,  512>(pxt, gx, gt, sub, o + 96);
    sample_direct_one<16,  512>(pyt, gy, gt, sub, o + 128);
    sample_direct_one<16,  512>(pzt, gz, gt, sub, o + 160);
}

extern "C" void kernel_launch(void* const* d_in, const int* in_sizes, int n_in,
                              void* d_out, int out_size, void* d_ws, size_t ws_size,
                              hipStream_t stream) {
    const float* x   = (const float*)d_in[0];
    const float* pxy = (const float*)d_in[1];
    const float* pxz = (const float*)d_in[2];
    const float* pyz = (const float*)d_in[3];
    const float* pxt = (const float*)d_in[4];
    const float* pyt = (const float*)d_in[5];
    const float* pzt = (const float*)d_in[6];
    float* out = (float*)d_out;

    if (ws_size >= WS_NEED_FULL) {
        char* wsb = (char*)d_ws;
        unsigned short* planes = (unsigned short*)wsb;
        unsigned int*   hist   = (unsigned int*)(wsb + OFF_HIST);
        unsigned int*   cursor = (unsigned int*)(wsb + OFF_CURSOR);
        unsigned short* keys   = (unsigned short*)(wsb + OFF_KEYS);
        f32x4*          xs     = (f32x4*)(wsb + OFF_XS);
        unsigned int*   pid    = (unsigned int*)(wsb + OFF_PID);

        hipMemsetAsync(hist, 0, NBINS * sizeof(unsigned int), stream);
        transpose3<64, 512, 512><<<dim3(512 * 8, 3), 256, 0, stream>>>(pxy, pxz, pyz, planes);
        transpose3<16, 512, 16><<<dim3(512, 3), 256, 0, stream>>>(pxt, pyt, pzt, planes + 25165824ul);
        hist_kernel<<<NPTS / 256, 256, 0, stream>>>(x, hist, keys);
        scan_kernel<<<1, 1024, 0, stream>>>(hist, cursor);
        scatter_kernel<<<NPTS / 256, 256, 0, stream>>>(x, keys, cursor, xs, pid);
        sample_sorted<<<(NPTS * 4) / 256, 256, 0, stream>>>(xs, pid, planes, out);
    } else if (ws_size >= WS_NEED_MID) {
        unsigned short* planes = (unsigned short*)d_ws;
        transpose3<64, 512, 512><<<dim3(512 * 8, 3), 256, 0, stream>>>(pxy, pxz, pyz, planes);
        transpose3<16, 512, 16><<<dim3(512, 3), 256, 0, stream>>>(pxt, pyt, pzt, planes + 25165824ul);
        sample_kernel<<<(NPTS * 4) / 256, 256, 0, stream>>>(x, planes, out);
    } else {
        sample_fallback<<<(NPTS * 4) / 256, 256, 0, stream>>>(x, pxy, pxz, pyz, pxt, pyt, pzt, out);
    }
}

// Round 4
// 359.488 us; speedup vs baseline: 1.0959x; 1.0364x over previous
//
#include <hip/hip_runtime.h>
#include <stdint.h>

#define NPTS 1048576
#define NBINS 32768

using u16x8 = __attribute__((ext_vector_type(8))) unsigned short;
using f32x4 = __attribute__((ext_vector_type(4))) float;

// workspace byte offsets (identical to round-2 layout, proven replay-safe)
#define OFF_HIST     51904512ul
#define OFF_CURSOR   52035584ul
#define OFF_KEYS     52166656ul
#define OFF_XS       54263808ul
#define OFF_PID      71041024ul
#define WS_NEED_FULL 75235328ul
#define WS_NEED_MID  51904512ul

// plane element offsets inside transposed bf16 buffer
#define PL_XY 0ul
#define PL_XZ 8388608ul
#define PL_YZ 16777216ul
#define PL_XT 25165824ul
#define PL_YT 25427968ul
#define PL_ZT 25690112ul

__device__ __forceinline__ float bf2f(unsigned short u) {
    union { unsigned int i; float f; } c; c.i = ((unsigned int)u) << 16; return c.f;
}
__device__ __forceinline__ unsigned int f2bf_bits(float f) {
    union { float f; unsigned int i; } c; c.f = f;
    unsigned int i = c.i;
    i += 0x7fffu + ((i >> 16) & 1u);   // round-to-nearest-even
    return i >> 16;
}
__device__ __forceinline__ unsigned int spread3(unsigned int v) {
    v &= 31u;
    v = (v | (v << 8)) & 0x100Fu;
    v = (v | (v << 4)) & 0x10C3u;
    v = (v | (v << 2)) & 0x1249u;   // bits at 0,3,6,9,12
    return v;
}

// ---------------------------------------------------------------------------
// Phase 1: transpose (C=32, H, W) fp32 -> (H, W, C=32) bf16 (round-2 verbatim)
// ---------------------------------------------------------------------------
template<int WC, int H, int W>
__global__ __launch_bounds__(256) void transpose3(const float* __restrict__ s0,
                                                  const float* __restrict__ s1,
                                                  const float* __restrict__ s2,
                                                  unsigned short* __restrict__ dst) {
    __shared__ float tile[32][WC + 1];
    const float* src = (blockIdx.y == 0) ? s0 : (blockIdx.y == 1) ? s1 : s2;
    constexpr int CH = W / WC;
    const int h  = blockIdx.x / CH;
    const int w0 = (blockIdx.x % CH) * WC;
    const int HW = H * W;
    const float* s = src + h * W + w0;
    for (int i = threadIdx.x; i < 32 * WC; i += 256) {
        int c = i / WC, w = i - c * WC;
        tile[c][w] = s[c * HW + w];
    }
    __syncthreads();
    unsigned int* d = (unsigned int*)(dst + (size_t)blockIdx.y * HW * 32
                                          + (size_t)(h * W + w0) * 32);
    for (int i = threadIdx.x; i < 16 * WC; i += 256) {
        int w = i >> 4, cp = i & 15;
        unsigned int lo = f2bf_bits(tile[cp * 2][w]);
        unsigned int hi = f2bf_bits(tile[cp * 2 + 1][w]);
        d[i] = lo | (hi << 16);
    }
}

// ---------------------------------------------------------------------------
// Sort pipeline (round-2 verbatim): hist -> scan -> scatter, 3D Morton 32^3
// ---------------------------------------------------------------------------
__global__ __launch_bounds__(256) void hist_kernel(const float* __restrict__ x,
                                                   unsigned int* __restrict__ hist,
                                                   unsigned short* __restrict__ keys) {
    int p = blockIdx.x * 256 + threadIdx.x;
    f32x4 xv = *(const f32x4*)(x + (size_t)p * 4);
    int bx = min(31, max(0, (int)((xv[0] + 1.0f) * 16.0f)));
    int by = min(31, max(0, (int)((xv[1] + 1.0f) * 16.0f)));
    int bz = min(31, max(0, (int)((xv[2] + 1.0f) * 16.0f)));
    unsigned int key = (spread3(bx) << 2) | (spread3(by) << 1) | spread3(bz);
    keys[p] = (unsigned short)key;
    atomicAdd(&hist[key], 1u);
}

__global__ __launch_bounds__(1024) void scan_kernel(const unsigned int* __restrict__ hist,
                                                    unsigned int* __restrict__ cursor) {
    __shared__ unsigned int part[1024];
    int t = threadIdx.x;
    unsigned int local[32];
    unsigned int s = 0;
    int base = t * 32;
#pragma unroll
    for (int j = 0; j < 32; ++j) { local[j] = s; s += hist[base + j]; }
    part[t] = s;
    __syncthreads();
    for (int off = 1; off < 1024; off <<= 1) {
        unsigned int v = 0;
        if (t >= off) v = part[t - off];
        __syncthreads();
        if (t >= off) part[t] += v;
        __syncthreads();
    }
    unsigned int chunkbase = part[t] - s;   // exclusive
#pragma unroll
    for (int j = 0; j < 32; ++j) cursor[base + j] = chunkbase + local[j];
}

__global__ __launch_bounds__(256) void scatter_kernel(const float* __restrict__ x,
                                                      const unsigned short* __restrict__ keys,
                                                      unsigned int* __restrict__ cursor,
                                                      f32x4* __restrict__ xs,
                                                      unsigned int* __restrict__ pid) {
    int p = blockIdx.x * 256 + threadIdx.x;
    f32x4 xv = *(const f32x4*)(x + (size_t)p * 4);
    unsigned int k = keys[p];
    unsigned int pos = atomicAdd(&cursor[k], 1u);
    xs[pos] = xv;
    pid[pos] = (unsigned int)p;
}

// ---------------------------------------------------------------------------
// Bilinear sample from (H,W,C) bf16 plane; 4 threads/point, 8 feats each
// ---------------------------------------------------------------------------
template<int W, int H, bool NT>
__device__ __forceinline__ void sample_one(const unsigned short* __restrict__ pl,
                                           float gw, float gh, int sub,
                                           float* __restrict__ o) {
    float ix = (gw + 1.0f) * 0.5f * (float)(W - 1);
    float iy = (gh + 1.0f) * 0.5f * (float)(H - 1);
    float fx0 = fminf(fmaxf(floorf(ix), 0.0f), (float)(W - 1));
    float fy0 = fminf(fmaxf(floorf(iy), 0.0f), (float)(H - 1));
    int ix0 = (int)fx0, iy0 = (int)fy0;
    int ix1 = min(ix0 + 1, W - 1), iy1 = min(iy0 + 1, H - 1);
    float wx = ix - fx0, wy = iy - fy0;
    float wx0 = 1.0f - wx, wy0 = 1.0f - wy;
    float w00 = wx0 * wy0, w01 = wx * wy0, w10 = wx0 * wy, w11 = wx * wy;
    const int base = sub * 8;
    u16x8 v00 = *(const u16x8*)(pl + ((iy0 * W + ix0) * 32 + base));
    u16x8 v01 = *(const u16x8*)(pl + ((iy0 * W + ix1) * 32 + base));
    u16x8 v10 = *(const u16x8*)(pl + ((iy1 * W + ix0) * 32 + base));
    u16x8 v11 = *(const u16x8*)(pl + ((iy1 * W + ix1) * 32 + base));
    f32x4 r0, r1;
#pragma unroll
    for (int j = 0; j < 4; ++j)
        r0[j] = bf2f(v00[j]) * w00 + bf2f(v01[j]) * w01
              + bf2f(v10[j]) * w10 + bf2f(v11[j]) * w11;
#pragma unroll
    for (int j = 0; j < 4; ++j)
        r1[j] = bf2f(v00[4 + j]) * w00 + bf2f(v01[4 + j]) * w01
              + bf2f(v10[4 + j]) * w10 + bf2f(v11[4 + j]) * w11;
    if (NT) {
        __builtin_nontemporal_store(r0, (f32x4*)(o));
        __builtin_nontemporal_store(r1, (f32x4*)(o + 4));
    } else {
        *(f32x4*)(o)     = r0;
        *(f32x4*)(o + 4) = r1;
    }
}

// One pass over the SAME sorted array: one big plane + one t-plane.
// xs element = original (x,y,z,t); lanes L0,L1 pick the big-plane coords,
// lane LT picks the t-plane's W coordinate, lane 3 is always t (H coord).
template<size_t BIGOFF, size_t TOFF, int L0, int L1, int LT, int OUT1, int OUT2>
__global__ __launch_bounds__(256) void sample_pass(const f32x4* __restrict__ xs,
                                                   const unsigned int* __restrict__ pid,
                                                   const unsigned short* __restrict__ planes,
                                                   float* __restrict__ out) {
    int cpx = gridDim.x >> 3;
    int bid = blockIdx.x;
    int swz = (bid & 7) * cpx + (bid >> 3);      // XCD-contiguous Morton ranges
    int tid = swz * 256 + threadIdx.x;
    int s   = tid >> 2;
    int sub = tid & 3;
    f32x4 v = xs[s];
    unsigned int p = pid[s];
    p = min(p, (unsigned int)(NPTS - 1));        // OOB insurance
    float g0 = (v[L0] * 0.5f + 0.5f) * 2.0f - 1.0f;
    float g1 = (v[L1] * 0.5f + 0.5f) * 2.0f - 1.0f;
    float gw = (v[LT] * 0.5f + 0.5f) * 2.0f - 1.0f;
    float gt = (v[3]  * 0.5f + 0.5f) * 2.0f - 1.0f;
    float* o = out + (size_t)p * 192 + sub * 8;
    sample_one<512, 512, true>(planes + BIGOFF, g0, g1, sub, o + OUT1);
    sample_one<16,  512, true>(planes + TOFF,   gw, gt, sub, o + OUT2);
}

// ---------------------------------------------------------------------------
// MID fallback: unsorted single-pass over all 6 planes (round-1 kernel)
// ---------------------------------------------------------------------------
__device__ __forceinline__ void sample_all(f32x4 xv, int sub,
                                           const unsigned short* __restrict__ ws,
                                           float* __restrict__ o) {
    float gx = (xv[0] * 0.5f + 0.5f) * 2.0f - 1.0f;
    float gy = (xv[1] * 0.5f + 0.5f) * 2.0f - 1.0f;
    float gz = (xv[2] * 0.5f + 0.5f) * 2.0f - 1.0f;
    float gt = (xv[3] * 0.5f + 0.5f) * 2.0f - 1.0f;
    sample_one<512, 512, true>(ws + PL_XY, gx, gy, sub, o + 0);
    sample_one<512, 512, true>(ws + PL_XZ, gx, gz, sub, o + 32);
    sample_one<512, 512, true>(ws + PL_YZ, gy, gz, sub, o + 64);
    sample_one<16,  512, true>(ws + PL_XT, gx, gt, sub, o + 96);
    sample_one<16,  512, true>(ws + PL_YT, gy, gt, sub, o + 128);
    sample_one<16,  512, true>(ws + PL_ZT, gz, gt, sub, o + 160);
}

__global__ __launch_bounds__(256) void sample_kernel(const float* __restrict__ x,
                                                     const unsigned short* __restrict__ ws,
                                                     float* __restrict__ out) {
    int tid = blockIdx.x * 256 + threadIdx.x;
    int p   = tid >> 2;
    int sub = tid & 3;
    f32x4 xv = *(const f32x4*)(x + (size_t)p * 4);
    sample_all(xv, sub, ws, out + (size_t)p * 192 + sub * 8);
}

// last-resort direct fp32 fallback
template<int W, int H>
__device__ __forceinline__ void sample_direct_one(const float* __restrict__ pl,
                                                  float gw, float gh, int sub,
                                                  float* __restrict__ o) {
    float ix = (gw + 1.0f) * 0.5f * (float)(W - 1);
    float iy = (gh + 1.0f) * 0.5f * (float)(H - 1);
    float fx0 = fminf(fmaxf(floorf(ix), 0.0f), (float)(W - 1));
    float fy0 = fminf(fmaxf(floorf(iy), 0.0f), (float)(H - 1));
    int ix0 = (int)fx0, iy0 = (int)fy0;
    int ix1 = min(ix0 + 1, W - 1), iy1 = min(iy0 + 1, H - 1);
    float wx = ix - fx0, wy = iy - fy0;
    float wx0 = 1.0f - wx, wy0 = 1.0f - wy;
    float w00 = wx0 * wy0, w01 = wx * wy0, w10 = wx0 * wy, w11 = wx * wy;
    const int HW = W * H;
    int a00 = iy0 * W + ix0, a01 = iy0 * W + ix1;
    int a10 = iy1 * W + ix0, a11 = iy1 * W + ix1;
    const float* b = pl + (size_t)sub * 8 * HW;
#pragma unroll
    for (int j = 0; j < 8; ++j) {
        o[j] = b[a00] * w00 + b[a01] * w01 + b[a10] * w10 + b[a11] * w11;
        b += HW;
    }
}

__global__ __launch_bounds__(256) void sample_fallback(const float* __restrict__ x,
    const float* __restrict__ pxy, const float* __restrict__ pxz,
    const float* __restrict__ pyz, const float* __restrict__ pxt,
    const float* __restrict__ pyt, const float* __restrict__ pzt,
    float* __restrict__ out) {
    int tid = blockIdx.x * 256 + threadIdx.x;
    int p   = tid >> 2;
    int sub = tid & 3;
    f32x4 xv = *(const f32x4*)(x + (size_t)p * 4);
    float gx = (xv[0] * 0.5f + 0.5f) * 2.0f - 1.0f;
    float gy = (xv[1] * 0.5f + 0.5f) * 2.0f - 1.0f;
    float gz = (xv[2] * 0.5f + 0.5f) * 2.0f - 1.0f;
    float gt = (xv[3] * 0.5f + 0.5f) * 2.0f - 1.0f;
    float* o = out + (size_t)p * 192 + sub * 8;
    sample_direct_one<512, 512>(pxy, gx, gy, sub, o + 0);
    sample_direct_one<512, 512>(pxz, gx, gz, sub, o + 32);
    sample_direct_one<512, 512>(pyz, gy, gz, sub, o + 64);
    sample_direct_one<16,  512>(pxt, gx, gt, sub, o + 96);
    sample_direct_one<16,  512>(pyt, gy, gt, sub, o + 128);
    sample_direct_one<16,  512>(pzt, gz, gt, sub, o + 160);
}

extern "C" void kernel_launch(void* const* d_in, const int* in_sizes, int n_in,
                              void* d_out, int out_size, void* d_ws, size_t ws_size,
                              hipStream_t stream) {
    const float* x   = (const float*)d_in[0];
    const float* pxy = (const float*)d_in[1];
    const float* pxz = (const float*)d_in[2];
    const float* pyz = (const float*)d_in[3];
    const float* pxt = (const float*)d_in[4];
    const float* pyt = (const float*)d_in[5];
    const float* pzt = (const float*)d_in[6];
    float* out = (float*)d_out;

    if (ws_size >= WS_NEED_FULL) {
        char* wsb = (char*)d_ws;
        unsigned short* planes = (unsigned short*)wsb;
        unsigned int*   hist   = (unsigned int*)(wsb + OFF_HIST);
        unsigned int*   cursor = (unsigned int*)(wsb + OFF_CURSOR);
        unsigned short* keys   = (unsigned short*)(wsb + OFF_KEYS);
        f32x4*          xs     = (f32x4*)(wsb + OFF_XS);
        unsigned int*   pid    = (unsigned int*)(wsb + OFF_PID);

        hipMemsetAsync(hist, 0, NBINS * sizeof(unsigned int), stream);
        transpose3<64, 512, 512><<<dim3(512 * 8, 3), 256, 0, stream>>>(pxy, pxz, pyz, planes);
        transpose3<16, 512, 16><<<dim3(512, 3), 256, 0, stream>>>(pxt, pyt, pzt, planes + PL_XT);
        hist_kernel<<<NPTS / 256, 256, 0, stream>>>(x, hist, keys);
        scan_kernel<<<1, 1024, 0, stream>>>(hist, cursor);
        scatter_kernel<<<NPTS / 256, 256, 0, stream>>>(x, keys, cursor, xs, pid);
        sample_pass<PL_XY, PL_XT, 0, 1, 0, 0,  96><<<(NPTS * 4) / 256, 256, 0, stream>>>(xs, pid, planes, out);
        sample_pass<PL_XZ, PL_ZT, 0, 2, 2, 32, 160><<<(NPTS * 4) / 256, 256, 0, stream>>>(xs, pid, planes, out);
        sample_pass<PL_YZ, PL_YT, 1, 2, 1, 64, 128><<<(NPTS * 4) / 256, 256, 0, stream>>>(xs, pid, planes, out);
    } else if (ws_size >= WS_NEED_MID) {
        unsigned short* planes = (unsigned short*)d_ws;
        transpose3<64, 512, 512><<<dim3(512 * 8, 3), 256, 0, stream>>>(pxy, pxz, pyz, planes);
        transpose3<16, 512, 16><<<dim3(512, 3), 256, 0, stream>>>(pxt, pyt, pzt, planes + PL_XT);
        sample_kernel<<<(NPTS * 4) / 256, 256, 0, stream>>>(x, planes, out);
    } else {
        sample_fallback<<<(NPTS * 4) / 256, 256, 0, stream>>>(x, pxy, pxz, pyz, pxt, pyt, pzt, out);
    }
}